// Round 22
// baseline (149.789 us; speedup 1.0000x reference)
//
#include <hip/hip_runtime.h>
#include <math.h>

// KerasCustomMappingLayer: B=32768 rows x H=512 sequential steps, out (B,H,6) f32.
//
// R22 = R19/R21 (proven 142.6us) with ONE structural change: ZERO in-loop
// block barriers.
//   - s_w wall table precomputed for ALL H at setup (8KB, read-only after
//     the single setup __syncthreads) -- no per-phase regeneration, so the
//     per-phase PBAR loses its only purpose.
//   - s_lk deleted; consumers compute lk = lm*rel[5H+k] inline (identical
//     op => bit-identical values).
//   - bd_xy aliased INTO bd_pk: B overwrites bd_pk[2kk+par].x with _c after
//     its last read of that slot (same-address program order); C reads the
//     .x of both par slots. Saves 4KB -> LDS ~17.5KB -> 8 blocks/CU kept.
//   - Phase loop: A; WF; B; WF; C; WF. All fences wave-local (s_waitcnt
//     lgkmcnt(0), proven R18/R19). Waves free-run -> natural phase drift
//     between the 32 resident waves/CU (the R20 overlap goal WITHOUT
//     artificial spins, which regressed; and unlike R15, B keeps its
//     table form -- no serial-loop VALU added).
// R19: no dead wrap-prefetch. R17: cross-phase register prefetch; barriers
// never drain vmcnt. R14: pair-split B + {-inf,+inf}-head wall table.
// R12: HALF=128. R11: packed bd_*, folded advance (+0.0 bit-safe).
// Numerics: carry path bit-identical to numpy fp32 (contract off, IEEE
// div/sqrt); outputs *1/512 pow2-exact, *1/384 <=1ulp output-only
// (absmax 0.0078125 stable R8-R21).
// Frozen: plain stores (R2/R4), dense global access (R1), no VGPR squeeze
// (R5), no sched_barrier (R15), no desync spins (R20), single-axis (R10).

#define H 512
#define RPB 4      // rows per block = waves per block
#define HALF 128   // k-steps staged per phase
#define NPH (H / HALF)
#define JPP (HALF / 64)   // j-iterations per phase
#define SLOTS 5    // 5*32 pairs = 160 >= max segments intersecting a phase

typedef float v2f __attribute__((ext_vector_type(2)));
typedef float v4f __attribute__((ext_vector_type(4)));

// wave-local LDS fence (cross-lane visibility within the wave)
#define WF() do { \
    asm volatile("s_waitcnt lgkmcnt(0)" ::: "memory"); \
} while (0)

__global__ __launch_bounds__(256, 4)
void construct_map_seg(const float* __restrict__ mapvars,
                       const float* __restrict__ rel,
                       const float* __restrict__ start_pos,
                       const float* __restrict__ lmul,
                       const int* __restrict__ nfse_p,
                       float* __restrict__ out)
{
#pragma clang fp contract(off)
    __shared__ short seg_list[H + 8];
    __shared__ int   nseg_s;
    __shared__ int   s_S[NPH];            // first segment intersecting each phase
    __shared__ float2 s_w[H * 2];         // FULL-H wall table; heads {-inf,+inf}; read-only after setup
    __shared__ float2 bd_pk[RPB][HALF * 2]; // per-wave {d_or_r, adv}; B overwrites .x with _c
    __shared__ float  bd_h[RPB][2];       // per-wave phase-crossing carry per chain

    const int tid = threadIdx.x;
    const int w = tid >> 6;
    const int lane = tid & 63;
    const int pair = lane >> 1;
    const int par = lane & 1;
    const int row = blockIdx.x * RPB + w;

    const float WL = (float)(0.05 * 512.0);
    const float WR = (float)(0.95 * 512.0);
    const float WT = (float)(0.05 * 384.0);
    const float WB = (float)(0.95 * 384.0);

    const float lm = lmul[0];

    // ---- setup: segment list (64 threads) + full wall table (all threads) ----
    if (tid < 64) {
        int base = 0;
        for (int c = 0; c < H / 64; ++c) {
            int k = c * 64 + tid;
            float lk = __fmul_rn(lm, rel[5 * H + k]);
            bool isr = (k == 0) || (lk > 192.0f);
            unsigned long long m = __ballot(isr);
            int idx = base + __popcll(m & ((1ull << tid) - 1ull));
            if (isr) seg_list[idx] = (short)k;
            base += __popcll(m);
        }
        if (tid == 0) { seg_list[base] = (short)H; nseg_s = base; }
        if (tid < NPH) {
            int kb = tid * HALF;
            int lo = 0, hi = base + 1;
            while (lo < hi) { int m = (lo + hi) >> 1; if ((int)seg_list[m] <= kb) lo = m + 1; else hi = m; }
            s_S[tid] = lo - 1;                     // seg_list[0]=0 => S>=0
        }
    }
    for (int i = tid; i < H * 2; i += 256) {       // full-H wall table
        const int k = i >> 1, prw = i & 1;
        float lk = __fmul_rn(lm, rel[5 * H + k]);
        bool head = lk > 192.0f;
        float hl = __fmul_rn(lk, 0.5f);
        float blo = prw ? WT : WL;
        float bhi = prw ? WB : WR;
        v2f w2 = {head ? -INFINITY : __fadd_rn(blo, hl),
                  head ?  INFINITY : __fadd_rn(bhi, -hl)};
        *(v2f*)&s_w[i] = w2;
    }
    __syncthreads();                               // the ONLY block barrier

    const int nseg = nseg_s;
    const bool nfse = (nfse_p[0] != 0);
    const float sx = start_pos[0], sy = start_pos[1];

    // fresh-segment init for k==0: start_pos unless k==0 is itself a rerand head
    const bool head0 = __fmul_rn(lm, rel[5 * H]) > 192.0f;
    const float pinit0 = head0 ? 0.0f : (par ? sy : sx);

    const float* rowp = mapvars + (size_t)row * (4 * H);
    float* orow = out + (size_t)row * (H * 6);

    // ---- cross-phase register prefetch of mapvars (8 VGPRs) ----
    float pf[JPP][4];
#pragma unroll
    for (int j = 0; j < JPP; ++j) {
        const int k = lane + 64 * j;                  // phase 0
        pf[j][0] = rowp[k];
        pf[j][1] = rowp[H + k];
        pf[j][2] = rowp[2 * H + k];
        pf[j][3] = rowp[3 * H + k];
    }

    for (int h = 0; h < NPH; ++h) {
        const int kb = h * HALF;
        const int kend = kb + HALF;
        const int kbn = ((h + 1) & (NPH - 1)) * HALF; // next phase base (prefetch only)
        float o2r[JPP], o3r[JPP], e1r[JPP], e2r[JPP];
        bool  islr[JPP];

        // ---- A: consume prefetched regs, compute, issue next-phase loads ----
#pragma unroll
        for (int j = 0; j < JPP; ++j) {
            const int kk = lane + 64 * j;
            const int k = kb + kk;
            float m0 = pf[j][0];
            float m1 = pf[j][1];
            float m2 = pf[j][2];
            float m3 = pf[j][3];
            if (h + 1 < NPH) {                        // no dead wrap-prefetch (R19)
                const int kn = kbn + kk;
                pf[j][0] = rowp[kn];
                pf[j][1] = rowp[H + kn];
                pf[j][2] = rowp[2 * H + kn];
                pf[j][3] = rowp[3 * H + kn];
            }
            float sln  = rel[H + k];
            float scos = rel[3 * H + k];
            float ssin = rel[4 * H + k];
            float lk   = __fmul_rn(lm, rel[5 * H + k]);   // == old s_lk[k], same op
            float isf  = rel[k];                          // is_slider (L2-broadcast)

            float len1 = __fsqrt_rn(__fadd_rn(__fmul_rn(m0, m0), __fmul_rn(m2, m2)));
            float ck = __fdiv_rn(m0, len1);
            float sk = __fdiv_rn(m2, len1);
            float len2 = __fsqrt_rn(__fadd_rn(__fmul_rn(m1, m1), __fmul_rn(m3, m3)));
            float ck2 = __fdiv_rn(m1, len2);
            float sk2 = __fdiv_rn(m3, len2);

            float dx = __fmul_rn(lk, ck);
            float dy = __fmul_rn(lk, sk);
            float rx = __fadd_rn(256.0f, __fmul_rn(256.0f, m0));
            float ry = __fadd_rn(192.0f, __fmul_rn(192.0f, m2));
            float e1 = __fmul_rn(ck2, sln);
            float e2 = __fmul_rn(sk2, sln);
            bool rr  = lk > 192.0f;                   // head position
            bool isl = isf != 0.0f;
            float oa = __fadd_rn(__fmul_rn(ck2, scos), -__fmul_rn(sk2, ssin));
            float ob = __fadd_rn(__fmul_rn(ck2, ssin),  __fmul_rn(sk2, scos));
            o2r[j] = isl ? oa : (rr ? ck2 : ck);
            o3r[j] = isl ? ob : (rr ? sk2 : sk);
            e1r[j] = e1; e2r[j] = e2;
            islr[j] = isl;

            bool adv = isl && nfse;
            v4f pk4 = {rr ? rx : dx, adv ? e1 : 0.0f,
                       rr ? ry : dy, adv ? e2 : 0.0f};
            *(v4f*)&bd_pk[w][2 * kk] = pk4;           // one b128 store
        }
        WF();   // bd_pk visible wave-wide

        // ---- B: serial carry chain, pair-split; result written into bd_pk.x ----
        {
            const int S = s_S[h];
#pragma unroll
            for (int slot = 0; slot < SLOTS; ++slot) {
                const int sid = S + pair + 32 * slot;
                if (sid < nseg) {
                    const int k0 = seg_list[sid];
                    const int k1 = seg_list[sid + 1];
                    const int lo = (k0 > kb) ? k0 : kb;
                    const int hi = (k1 < kend) ? k1 : kend;
                    if (lo < hi) {
                        float p;
                        if (k0 < kb)      p = bd_h[w][par];     // crossing-in
                        else if (k0 == 0) p = pinit0;
                        else              p = 0.0f;             // fresh head segment
                        for (int k = lo; k < hi; ++k) {
                            const int kk = k - kb;
                            float2 w2 = s_w[2 * k + par];       // global-k index
                            float2 pk = bd_pk[w][2 * kk + par];
                            float d = pk.x, a = pk.y;
                            float ad = fabsf(d);
                            float cd = (p < w2.x) ? ad
                                     : ((p > w2.y) ? -ad
                                     : (((p > w2.x) && (p < w2.y)) ? d : 0.0f));
                            float _c = __fadd_rn(p, cd);        // head: 0 + r = r
                            bd_pk[w][2 * kk + par].x = _c;      // alias write AFTER last read
                            p = __fadd_rn(_c, a);               // +0.0 bit-safe
                        }
                        if (k1 > kend) bd_h[w][par] = p;        // crossing-out (unique)
                    }
                }
            }
        }
        WF();   // _c values + bd_h visible wave-wide

        // ---- C: output assembly, dense stores (pure LDS + store) ----
#pragma unroll
        for (int j = 0; j < JPP; ++j) {
            const int kk = lane + 64 * j;
            const int k = kb + kk;
            float _x = bd_pk[w][2 * kk + 0].x;
            float _y = bd_pk[w][2 * kk + 1].x;
            float o0 = __fmul_rn(_x, 1.0f / 512.0f);
            float o1 = __fmul_rn(_y, 1.0f / 384.0f);
            bool isl = islr[j];
            float o4 = o0, o5 = o1;
            if (isl) {
                o4 = __fmul_rn(__fadd_rn(_x, e1r[j]), 1.0f / 512.0f);
                o5 = __fmul_rn(__fadd_rn(_y, e2r[j]), 1.0f / 384.0f);
            }
            float* op = orow + (size_t)k * 6;
            v2f a = {o0, o1};
            v2f b = {o2r[j], o3r[j]};
            v2f c = {o4, o5};
            *(v2f*)(op)     = a;
            *(v2f*)(op + 2) = b;
            *(v2f*)(op + 4) = c;
        }
        WF();   // C's bd_pk reads drained before next A overwrites bd_pk
    }
}

extern "C" void kernel_launch(void* const* d_in, const int* in_sizes, int n_in,
                              void* d_out, int out_size, void* d_ws, size_t ws_size,
                              hipStream_t stream) {
    const float* mapvars = (const float*)d_in[0];
    const float* rel     = (const float*)d_in[1];
    const float* sp      = (const float*)d_in[2];
    const float* lm      = (const float*)d_in[3];
    const int*   nfse    = (const int*)d_in[4];
    float* out = (float*)d_out;

    const int B = in_sizes[0] / (4 * H);   // 32768
    hipLaunchKernelGGL(construct_map_seg, dim3(B / RPB), dim3(256), 0, stream,
                       mapvars, rel, sp, lm, nfse, out);
}

// Round 23
// 142.583 us; speedup vs baseline: 1.0505x; 1.0505x over previous
//
#include <hip/hip_runtime.h>
#include <math.h>

// KerasCustomMappingLayer: B=32768 rows x H=512 sequential steps, out (B,H,6) f32.
//
// R23 = exact revert to R19 (best proven: 142.6us). R22 (zero block barriers,
// s_w precomputed full-H, bd_xy aliased into bd_pk) regressed to 149.8 --
// SECOND failure of wave-local-only sync (R15: 157). Conclusion: the one
// block-barrier-per-phase structure (R18/R19) is a genuine local optimum of
// the sync-granularity axis: barriers keep the 4 waves' A-phase load bursts
// clustered (L2/burst locality) which beats free-run overlap on this chip.
// Axes explored & closed from this structure:
//   sync granularity: R15/R18/R19/R22 -> R19 optimal (1 PBAR/phase).
//   B LDS latency:    R16 neutral (compiler already pipelines).
//   B issue count:    R11/R13/R14 banked; further cuts cost occupancy.
//   occupancy:        R12 at HW max (8 blocks/CU, 32 waves).
//   traffic:          R8/R19 at minimum (~525MB incl. L3 absorption).
//   phase overlap:    R17 banked (reg prefetch + non-draining PBAR);
//                     R20 artificial desync falsified (-40us).
//   dead work:        R19 (wrap-prefetch), R21 (rel reload: neutral).
// Numerics: carry path bit-identical to numpy fp32 (contract off, IEEE
// div/sqrt); outputs *1/512 pow2-exact, *1/384 <=1ulp output-only
// (absmax 0.0078125 stable R8-R22).
// Frozen: plain stores (R2/R4), dense global access (R1), no VGPR squeeze
// (R5), no sched_barrier (R15), no desync spins (R20), single-axis (R10).

#define H 512
#define RPB 4      // rows per block = waves per block
#define HALF 128   // k-steps staged per phase
#define NPH (H / HALF)
#define JPP (HALF / 64)   // j-iterations per phase
#define SLOTS 5    // 5*32 pairs = 160 >= max segments intersecting a phase

typedef float v2f __attribute__((ext_vector_type(2)));
typedef float v4f __attribute__((ext_vector_type(4)));

// block barrier WITHOUT vmcnt drain (LDS visibility across waves)
#define PBAR() do { \
    asm volatile("s_waitcnt lgkmcnt(0)" ::: "memory"); \
    __builtin_amdgcn_s_barrier(); \
} while (0)

// wave-local LDS fence (cross-lane visibility within the wave)
#define WF() do { \
    asm volatile("s_waitcnt lgkmcnt(0)" ::: "memory"); \
} while (0)

__global__ __launch_bounds__(256, 4)
void construct_map_seg(const float* __restrict__ mapvars,
                       const float* __restrict__ rel,
                       const float* __restrict__ start_pos,
                       const float* __restrict__ lmul,
                       const int* __restrict__ nfse_p,
                       float* __restrict__ out)
{
#pragma clang fp contract(off)
    __shared__ float s_lk[H];
    __shared__ short seg_list[H + 8];
    __shared__ int   nseg_s;
    __shared__ int   s_S[NPH];              // first segment intersecting each phase
    __shared__ float2 s_w[2][HALF * 2];     // double-buffered wall table; heads {-inf,+inf}
    __shared__ float2 bd_pk[RPB][HALF * 2]; // per-wave: {d_or_r, advance} per (kk,par)
    __shared__ float2 bd_xy[RPB][HALF];     // per-wave: {_x,_y} results
    __shared__ float  bd_h[RPB][2];         // per-wave: phase-crossing carry per chain

    const int tid = threadIdx.x;
    const int w = tid >> 6;
    const int lane = tid & 63;
    const int pair = lane >> 1;
    const int par = lane & 1;
    const int row = blockIdx.x * RPB + w;

    const float WL = (float)(0.05 * 512.0);
    const float WR = (float)(0.95 * 512.0);
    const float WT = (float)(0.05 * 384.0);
    const float WB = (float)(0.95 * 384.0);

    const float lm = lmul[0];
    for (int i = tid; i < H; i += 256)
        s_lk[i] = __fmul_rn(lm, rel[5 * H + i]);   // l = lmul * note_dist
    __syncthreads();

    // segment list: starts = {0} U {k : l[k] > 192}  (k-only, all rows share)
    if (tid < 64) {
        int base = 0;
        for (int c = 0; c < H / 64; ++c) {
            int k = c * 64 + tid;
            bool isr = (k == 0) || (s_lk[k] > 192.0f);
            unsigned long long m = __ballot(isr);
            int idx = base + __popcll(m & ((1ull << tid) - 1ull));
            if (isr) seg_list[idx] = (short)k;
            base += __popcll(m);
        }
        if (tid == 0) { seg_list[base] = (short)H; nseg_s = base; }
        // per-phase first-intersecting segment: S_h = (first idx > kb) - 1
        if (tid < NPH) {
            int kb = tid * HALF;
            int lo = 0, hi = base + 1;
            while (lo < hi) { int m = (lo + hi) >> 1; if ((int)seg_list[m] <= kb) lo = m + 1; else hi = m; }
            s_S[tid] = lo - 1;                     // seg_list[0]=0 => S>=0
        }
    }
    // prologue: wall table for phase 0 into buffer 0
    {
        const int i = tid;
        const int kkw = i >> 1, prw = i & 1;
        float lk = s_lk[kkw];                      // phase 0: kb = 0
        bool head = lk > 192.0f;
        float hl = __fmul_rn(lk, 0.5f);
        float blo = prw ? WT : WL;
        float bhi = prw ? WB : WR;
        v2f w2 = {head ? -INFINITY : __fadd_rn(blo, hl),
                  head ?  INFINITY : __fadd_rn(bhi, -hl)};
        *(v2f*)&s_w[0][i] = w2;
    }
    __syncthreads();

    const int nseg = nseg_s;
    const bool nfse = (nfse_p[0] != 0);
    const float sx = start_pos[0], sy = start_pos[1];

    // fresh-segment init for k==0: start_pos unless k==0 is itself a rerand head
    const bool head0 = s_lk[0] > 192.0f;
    const float pinit0 = head0 ? 0.0f : (par ? sy : sx);

    const float* rowp = mapvars + (size_t)row * (4 * H);
    float* orow = out + (size_t)row * (H * 6);

    // ---- cross-phase register prefetch of mapvars (8 VGPRs) ----
    float pf[JPP][4];
#pragma unroll
    for (int j = 0; j < JPP; ++j) {
        const int k = lane + 64 * j;                  // phase 0
        pf[j][0] = rowp[k];
        pf[j][1] = rowp[H + k];
        pf[j][2] = rowp[2 * H + k];
        pf[j][3] = rowp[3 * H + k];
    }

    for (int h = 0; h < NPH; ++h) {
        const int kb = h * HALF;
        const int kend = kb + HALF;
        const int kbn = ((h + 1) & (NPH - 1)) * HALF; // next phase base
        float o2r[JPP], o3r[JPP], e1r[JPP], e2r[JPP];

        if (h) PBAR();   // the ONLY block barrier per phase (no vmcnt drain)

        // ---- wall table for NEXT phase into buffer (h+1)&1 ----
        {
            const int i = tid;
            const int kkw = i >> 1, prw = i & 1;
            float lk = s_lk[kbn + kkw];
            bool head = lk > 192.0f;
            float hl = __fmul_rn(lk, 0.5f);
            float blo = prw ? WT : WL;
            float bhi = prw ? WB : WR;
            v2f w2 = {head ? -INFINITY : __fadd_rn(blo, hl),
                      head ?  INFINITY : __fadd_rn(bhi, -hl)};
            *(v2f*)&s_w[(h + 1) & 1][i] = w2;
        }

        // ---- A: consume prefetched regs, compute, issue next-phase loads ----
#pragma unroll
        for (int j = 0; j < JPP; ++j) {
            const int kk = lane + 64 * j;
            const int k = kb + kk;
            float m0 = pf[j][0];
            float m1 = pf[j][1];
            float m2 = pf[j][2];
            float m3 = pf[j][3];
            if (h + 1 < NPH) {                        // no dead wrap-prefetch (R19)
                const int kn = kbn + kk;
                pf[j][0] = rowp[kn];
                pf[j][1] = rowp[H + kn];
                pf[j][2] = rowp[2 * H + kn];
                pf[j][3] = rowp[3 * H + kn];
            }
            float sln  = rel[H + k];
            float scos = rel[3 * H + k];
            float ssin = rel[4 * H + k];
            float lk  = s_lk[k];
            float isf = rel[k];                       // is_slider (L2-broadcast)

            float len1 = __fsqrt_rn(__fadd_rn(__fmul_rn(m0, m0), __fmul_rn(m2, m2)));
            float ck = __fdiv_rn(m0, len1);
            float sk = __fdiv_rn(m2, len1);
            float len2 = __fsqrt_rn(__fadd_rn(__fmul_rn(m1, m1), __fmul_rn(m3, m3)));
            float ck2 = __fdiv_rn(m1, len2);
            float sk2 = __fdiv_rn(m3, len2);

            float dx = __fmul_rn(lk, ck);
            float dy = __fmul_rn(lk, sk);
            float rx = __fadd_rn(256.0f, __fmul_rn(256.0f, m0));
            float ry = __fadd_rn(192.0f, __fmul_rn(192.0f, m2));
            float e1 = __fmul_rn(ck2, sln);
            float e2 = __fmul_rn(sk2, sln);
            bool rr  = lk > 192.0f;                   // head position
            bool isl = isf != 0.0f;
            float oa = __fadd_rn(__fmul_rn(ck2, scos), -__fmul_rn(sk2, ssin));
            float ob = __fadd_rn(__fmul_rn(ck2, ssin),  __fmul_rn(sk2, scos));
            o2r[j] = isl ? oa : (rr ? ck2 : ck);
            o3r[j] = isl ? ob : (rr ? sk2 : sk);
            e1r[j] = e1; e2r[j] = e2;

            bool adv = isl && nfse;
            v4f pk4 = {rr ? rx : dx, adv ? e1 : 0.0f,
                       rr ? ry : dy, adv ? e2 : 0.0f};
            *(v4f*)&bd_pk[w][2 * kk] = pk4;           // one b128 store
        }
        WF();   // bd_pk visible wave-wide (per-wave array; cross-lane in-wave)

        // ---- B: serial carry chain, pair-split (R14 form) ----
        {
            const int S = s_S[h];
            const float2* swb = &s_w[h & 1][0];
#pragma unroll
            for (int slot = 0; slot < SLOTS; ++slot) {
                const int sid = S + pair + 32 * slot;
                if (sid < nseg) {
                    const int k0 = seg_list[sid];
                    const int k1 = seg_list[sid + 1];
                    const int lo = (k0 > kb) ? k0 : kb;
                    const int hi = (k1 < kend) ? k1 : kend;
                    if (lo < hi) {
                        float p;
                        if (k0 < kb)      p = bd_h[w][par];     // crossing-in
                        else if (k0 == 0) p = pinit0;
                        else              p = 0.0f;             // fresh head segment
                        for (int k = lo; k < hi; ++k) {
                            const int kk = k - kb;
                            float2 w2 = swb[2 * kk + par];
                            float2 pk = bd_pk[w][2 * kk + par];
                            float d = pk.x, a = pk.y;
                            float ad = fabsf(d);
                            float cd = (p < w2.x) ? ad
                                     : ((p > w2.y) ? -ad
                                     : (((p > w2.x) && (p < w2.y)) ? d : 0.0f));
                            float _c = __fadd_rn(p, cd);        // head: 0 + r = r
                            ((float*)&bd_xy[w][kk])[par] = _c;
                            p = __fadd_rn(_c, a);               // +0.0 bit-safe
                        }
                        if (k1 > kend) bd_h[w][par] = p;        // crossing-out (unique)
                    }
                }
            }
        }
        WF();   // bd_xy + bd_h visible wave-wide

        // ---- C: output assembly, dense stores ----
#pragma unroll
        for (int j = 0; j < JPP; ++j) {
            const int kk = lane + 64 * j;
            const int k = kb + kk;
            float2 xy = bd_xy[w][kk];
            float _x = xy.x, _y = xy.y;
            float o0 = __fmul_rn(_x, 1.0f / 512.0f);
            float o1 = __fmul_rn(_y, 1.0f / 384.0f);
            bool isl = rel[k] != 0.0f;
            float o4 = o0, o5 = o1;
            if (isl) {
                o4 = __fmul_rn(__fadd_rn(_x, e1r[j]), 1.0f / 512.0f);
                o5 = __fmul_rn(__fadd_rn(_y, e2r[j]), 1.0f / 384.0f);
            }
            float* op = orow + (size_t)k * 6;
            v2f a = {o0, o1};
            v2f b = {o2r[j], o3r[j]};
            v2f c = {o4, o5};
            *(v2f*)(op)     = a;
            *(v2f*)(op + 2) = b;
            *(v2f*)(op + 4) = c;
        }
        // no fence here: C's bd_xy reads are drained by the next phase's
        // A->B WF (same wave); s_w buffer reuse is ordered by the phase PBAR.
    }
}

extern "C" void kernel_launch(void* const* d_in, const int* in_sizes, int n_in,
                              void* d_out, int out_size, void* d_ws, size_t ws_size,
                              hipStream_t stream) {
    const float* mapvars = (const float*)d_in[0];
    const float* rel     = (const float*)d_in[1];
    const float* sp      = (const float*)d_in[2];
    const float* lm      = (const float*)d_in[3];
    const int*   nfse    = (const int*)d_in[4];
    float* out = (float*)d_out;

    const int B = in_sizes[0] / (4 * H);   // 32768
    hipLaunchKernelGGL(construct_map_seg, dim3(B / RPB), dim3(256), 0, stream,
                       mapvars, rel, sp, lm, nfse, out);
}